// Round 2
// baseline (3940.219 us; speedup 1.0000x reference)
//
#include <hip/hip_runtime.h>

// 8-layer transformer LM forward. V=128, E=512, L=8, H=8, B=4, T=1024.
// Wire format (deduced round 1): ALL float tensors are fp32 arrays holding
// bf16-rounded values; ints are int32; d_out is fp32 (524288 logits + 1 loss).
// Compute fp32 VALU this round; MFMA conversion next round once green.

#define V_  128
#define E_  512
#define L_  8
#define H_  8
#define B_  4
#define T_  1024
#define N_  (B_*T_)    // 4096 tokens
#define DH_ 64
#define E3_ 1536

// ---------------- embedding ----------------
__global__ void embed_kernel(const int* __restrict__ tok,
                             const float* __restrict__ emb,
                             float* __restrict__ x) {
    int idx = blockIdx.x * blockDim.x + threadIdx.x;
    if (idx >= N_ * E_) return;
    int n = idx >> 9;            // /512
    int e = idx & (E_ - 1);
    x[idx] = emb[tok[n] * E_ + e];
}

// ---------------- GEMM: C[n,o] = act(sum_k A[n,k]*W[o,k] + bias[o]) ----------------
// A fp32 [M,K], W fp32 [Nout,K] (row-major, K contiguous -> A·W^T), C fp32 [M,Nout].
// Tiles: BM=BN=64, BK=16; 256 threads; 4x4 outputs/thread.
__global__ __launch_bounds__(256) void gemm_bias(
    const float* __restrict__ A, const float* __restrict__ W,
    const float* __restrict__ bias, float* __restrict__ C,
    int M, int Nout, int K, int relu)
{
    __shared__ float As[16][64];
    __shared__ float Bs[16][64];
    int tid = threadIdx.x;
    int n0 = blockIdx.y * 64;
    int o0 = blockIdx.x * 64;
    int tr = tid >> 4, tc = tid & 15;       // 16x16 thread grid
    int lr = tid >> 2;                      // load row 0..63
    int lg = (tid & 3) << 2;                // load k-offset 0,4,8,12
    float acc[4][4] = {};
    const float* aBase = A + (size_t)(n0 + lr) * K + lg;
    const float* wBase = W + (size_t)(o0 + lr) * K + lg;
    for (int k0 = 0; k0 < K; k0 += 16) {
        float4 av = *(const float4*)(aBase + k0);
        float4 wv = *(const float4*)(wBase + k0);
        As[lg + 0][lr] = av.x; As[lg + 1][lr] = av.y;
        As[lg + 2][lr] = av.z; As[lg + 3][lr] = av.w;
        Bs[lg + 0][lr] = wv.x; Bs[lg + 1][lr] = wv.y;
        Bs[lg + 2][lr] = wv.z; Bs[lg + 3][lr] = wv.w;
        __syncthreads();
        #pragma unroll
        for (int kk = 0; kk < 16; ++kk) {
            float4 a4 = *(const float4*)&As[kk][tr << 2];
            float4 b4 = *(const float4*)&Bs[kk][tc << 2];
            float ar[4] = {a4.x, a4.y, a4.z, a4.w};
            float br[4] = {b4.x, b4.y, b4.z, b4.w};
            #pragma unroll
            for (int i = 0; i < 4; ++i)
                #pragma unroll
                for (int j = 0; j < 4; ++j)
                    acc[i][j] = fmaf(ar[i], br[j], acc[i][j]);
        }
        __syncthreads();
    }
    #pragma unroll
    for (int j = 0; j < 4; ++j) {
        int o = o0 + (tc << 2) + j;
        float bj = bias[o];
        #pragma unroll
        for (int i = 0; i < 4; ++i) {
            float v = acc[i][j] + bj;
            if (relu) v = fmaxf(v, 0.f);
            C[(size_t)(n0 + (tr << 2) + i) * Nout + o] = v;
        }
    }
}

// 64x64 tile GEMM helper on LDS: sacc[i][j] += sum_d Am[d][ra+i] * Bm[d][cb+j]
__device__ __forceinline__ void tile_gemm64(const float (*__restrict__ Am)[64],
                                            const float (*__restrict__ Bm)[64],
                                            int ra, int cb, float sacc[4][4]) {
    #pragma unroll 8
    for (int d = 0; d < 64; ++d) {
        float4 a4 = *(const float4*)&Am[d][ra];
        float4 b4 = *(const float4*)&Bm[d][cb];
        float ar[4] = {a4.x, a4.y, a4.z, a4.w};
        float br[4] = {b4.x, b4.y, b4.z, b4.w};
        #pragma unroll
        for (int i = 0; i < 4; ++i)
            #pragma unroll
            for (int j = 0; j < 4; ++j)
                sacc[i][j] = fmaf(ar[i], br[j], sacc[i][j]);
    }
}

// ---------------- attention ----------------
// Grid: (16 q-tiles, 32 b*h). One WG = 256 threads handles 64 queries of one head.
// Reference quirk: masked scores are ZERO (not -inf) and participate in softmax.
// Two passes over K tiles: pass1 builds per-row (max, sumexp); pass2 recomputes
// scores, forms unnormalized P in LDS, accumulates P·V. Scores never hit HBM.
__global__ __launch_bounds__(256) void attn_kernel(const float* __restrict__ qkv,
                                                   float* __restrict__ out)
{
    __shared__ float Qs[64][64];   // [d][qi]
    __shared__ float SK[64][64];   // K tile [d][ki]; reused as P [ki][qi] in pass2
    __shared__ float Vs[64][64];   // [ki][d]
    __shared__ float mp[64][16];
    __shared__ float zp[64][16];
    __shared__ float mfin[64];
    __shared__ float zfin[64];

    int tid = threadIdx.x;
    int qt = blockIdx.x;           // 0..15
    int bh = blockIdx.y;           // 0..31
    int b = bh >> 3, h = bh & 7;
    int q0 = qt * 64;
    int tr = tid >> 4, tc = tid & 15;
    int tr4 = tr << 2, tc4 = tc << 2;
    int lr = tid >> 2;             // 0..63
    int lg = (tid & 3) << 2;       // 0,4,8,12
    const float scale = 0.125f;    // 1/sqrt(64)
    size_t rowbase = (size_t)(b * T_) * E3_ + (size_t)h * (3 * DH_);

    // load Q tile transposed -> Qs[d][qi]
    #pragma unroll
    for (int rep = 0; rep < 4; ++rep) {
        int d = lg + rep * 16;
        float4 v = *(const float4*)&qkv[rowbase + (size_t)(q0 + lr) * E3_ + d];
        Qs[d + 0][lr] = v.x; Qs[d + 1][lr] = v.y; Qs[d + 2][lr] = v.z; Qs[d + 3][lr] = v.w;
    }

    float pm[4], pz[4];
    #pragma unroll
    for (int i = 0; i < 4; ++i) { pm[i] = -1e30f; pz[i] = 0.f; }

    // ---- pass 1: per-row running (max, sumexp) ----
    for (int kt = 0; kt < 16; ++kt) {
        int k0 = kt * 64;
        __syncthreads();   // previous tile's readers done before overwriting SK
        #pragma unroll
        for (int rep = 0; rep < 4; ++rep) {
            int d = lg + rep * 16;
            float4 v = *(const float4*)&qkv[rowbase + (size_t)(k0 + lr) * E3_ + DH_ + d];
            SK[d + 0][lr] = v.x; SK[d + 1][lr] = v.y; SK[d + 2][lr] = v.z; SK[d + 3][lr] = v.w;
        }
        __syncthreads();
        float s[4][4] = {};
        tile_gemm64(Qs, SK, tr4, tc4, s);
        #pragma unroll
        for (int i = 0; i < 4; ++i) {
            int qg = q0 + tr4 + i;
            #pragma unroll
            for (int j = 0; j < 4; ++j) {
                int kg = k0 + tc4 + j;
                float sv = (kg <= qg) ? s[i][j] * scale : 0.f;   // zero, not -inf!
                float mn = fmaxf(pm[i], sv);
                pz[i] = pz[i] * __expf(pm[i] - mn) + __expf(sv - mn);
                pm[i] = mn;
            }
        }
    }
    // merge 16 column-partials per row
    #pragma unroll
    for (int i = 0; i < 4; ++i) { mp[tr4 + i][tc] = pm[i]; zp[tr4 + i][tc] = pz[i]; }
    __syncthreads();
    if (tid < 64) {
        float m = -1e30f;
        #pragma unroll
        for (int c = 0; c < 16; ++c) m = fmaxf(m, mp[tid][c]);
        float z = 0.f;
        #pragma unroll
        for (int c = 0; c < 16; ++c) z += zp[tid][c] * __expf(mp[tid][c] - m);
        mfin[tid] = m; zfin[tid] = z;
    }
    __syncthreads();
    float rm[4];
    #pragma unroll
    for (int i = 0; i < 4; ++i) rm[i] = mfin[tr4 + i];

    // ---- pass 2: recompute scores, accumulate O = P·V ----
    float oacc[4][4] = {};
    for (int kt = 0; kt < 16; ++kt) {
        int k0 = kt * 64;
        __syncthreads();   // prior PV readers done before overwriting SK/Vs
        #pragma unroll
        for (int rep = 0; rep < 4; ++rep) {
            int d = lg + rep * 16;
            float4 kv = *(const float4*)&qkv[rowbase + (size_t)(k0 + lr) * E3_ + DH_ + d];
            SK[d + 0][lr] = kv.x; SK[d + 1][lr] = kv.y; SK[d + 2][lr] = kv.z; SK[d + 3][lr] = kv.w;
            float4 vv = *(const float4*)&qkv[rowbase + (size_t)(k0 + lr) * E3_ + 2 * DH_ + d];
            *(float4*)&Vs[lr][d] = vv;   // natural layout [ki][d]
        }
        __syncthreads();
        float s[4][4] = {};
        tile_gemm64(Qs, SK, tr4, tc4, s);
        __syncthreads();   // done reading SK as K; now overwrite with P
        #pragma unroll
        for (int i = 0; i < 4; ++i) {
            int qg = q0 + tr4 + i;
            #pragma unroll
            for (int j = 0; j < 4; ++j) {
                int kg = k0 + tc4 + j;
                float sv = (kg <= qg) ? s[i][j] * scale : 0.f;
                SK[tc4 + j][tr4 + i] = __expf(sv - rm[i]);   // P[ki][qi], unnormalized
            }
        }
        __syncthreads();
        tile_gemm64(SK, Vs, tr4, tc4, oacc);   // oacc[i][j] += P[k][q]·V[k][d]
    }
    // store: out[(b,q), h*64+d] = O / Z   (this IS the transpose-back + reshape)
    #pragma unroll
    for (int i = 0; i < 4; ++i) {
        int q = q0 + tr4 + i;
        float zi = 1.f / zfin[tr4 + i];
        #pragma unroll
        for (int j = 0; j < 4; ++j)
            out[(size_t)(b * T_ + q) * E_ + h * DH_ + tc4 + j] = oacc[i][j] * zi;
    }
}

// ---------------- residual add + LayerNorm ----------------
// out[n,:] = LN(a[n,:] + r[n,:]) * s + b ; one 256-thread block per row, 2 elems/thread
__global__ __launch_bounds__(256) void add_ln_kernel(
    const float* __restrict__ a, const float* __restrict__ r,
    const float* __restrict__ s, const float* __restrict__ bpar,
    float* __restrict__ out)
{
    int n = blockIdx.x;
    int tid = threadIdx.x;
    int e = tid * 2;
    float2 va = *(const float2*)&a[(size_t)n * E_ + e];
    float2 vr = *(const float2*)&r[(size_t)n * E_ + e];
    float v0 = va.x + vr.x, v1 = va.y + vr.y;

    __shared__ float red[4];
    int lane = tid & 63, w = tid >> 6;

    float lsum = v0 + v1;
    #pragma unroll
    for (int off = 32; off; off >>= 1) lsum += __shfl_down(lsum, off, 64);
    if (lane == 0) red[w] = lsum;
    __syncthreads();
    float mu = (red[0] + red[1] + red[2] + red[3]) * (1.f / 512.f);
    __syncthreads();

    float d0 = v0 - mu, d1 = v1 - mu;
    float lss = d0 * d0 + d1 * d1;
    #pragma unroll
    for (int off = 32; off; off >>= 1) lss += __shfl_down(lss, off, 64);
    if (lane == 0) red[w] = lss;
    __syncthreads();
    float var = (red[0] + red[1] + red[2] + red[3]) * (1.f / 512.f);
    float rstd = rsqrtf(var + 1e-5f);

    out[(size_t)n * E_ + e]     = d0 * rstd * s[e]     + bpar[e];
    out[(size_t)n * E_ + e + 1] = d1 * rstd * s[e + 1] + bpar[e + 1];
}

// ---------------- per-row loss + fp32 logits out ----------------
__global__ __launch_bounds__(128) void loss_row_kernel(
    const float* __restrict__ logits, const int* __restrict__ tgt,
    float* __restrict__ out_logits, float* __restrict__ rowloss)
{
    int n = blockIdx.x, i = threadIdx.x;
    float x = logits[(size_t)n * V_ + i];
    out_logits[(size_t)n * V_ + i] = x;

    __shared__ float redA[2], redB[2];
    __shared__ float xt;
    int lane = i & 63, w = i >> 6;
    if (i == tgt[n]) xt = x;

    float m = x;
    #pragma unroll
    for (int off = 32; off; off >>= 1) m = fmaxf(m, __shfl_down(m, off, 64));
    if (lane == 0) redA[w] = m;
    __syncthreads();
    m = fmaxf(redA[0], redA[1]);
    __syncthreads();

    float ev = __expf(x - m);
    float se = ev, sx = x;
    #pragma unroll
    for (int off = 32; off; off >>= 1) {
        se += __shfl_down(se, off, 64);
        sx += __shfl_down(sx, off, 64);
    }
    if (lane == 0) { redA[w] = se; redB[w] = sx; }
    __syncthreads();
    if (i == 0) {
        float seT = redA[0] + redA[1], sxT = redB[0] + redB[1];
        float lse = m + __logf(seT);
        float nll = lse - xt;                       // -logp[target]
        float smooth = lse - sxT * (1.f / 128.f);   // -mean(logp)
        rowloss[n] = 0.9f * nll + 0.1f * smooth;
    }
}

__global__ __launch_bounds__(256) void loss_reduce_kernel(
    const float* __restrict__ rowloss, float* __restrict__ out)
{
    int tid = threadIdx.x;
    float sm = 0.f;
    for (int idx = tid; idx < N_; idx += 256) sm += rowloss[idx];
    #pragma unroll
    for (int off = 32; off; off >>= 1) sm += __shfl_down(sm, off, 64);
    __shared__ float red[4];
    int lane = tid & 63, w = tid >> 6;
    if (lane == 0) red[w] = sm;
    __syncthreads();
    if (tid == 0) out[0] = (red[0] + red[1] + red[2] + red[3]) * (1.f / (float)N_);
}

extern "C" void kernel_launch(void* const* d_in, const int* in_sizes, int n_in,
                              void* d_out, int out_size, void* d_ws, size_t ws_size,
                              hipStream_t stream)
{
    (void)in_sizes; (void)n_in; (void)out_size; (void)ws_size;
    const int* toks     = (const int*)d_in[0];
    const int* tgts     = (const int*)d_in[1];
    const float* emb    = (const float*)d_in[2];
    const float* qkv_w  = (const float*)d_in[3];
    const float* qkv_b  = (const float*)d_in[4];
    const float* aff1_w = (const float*)d_in[5];
    const float* aff1_b = (const float*)d_in[6];
    const float* aff2_w = (const float*)d_in[7];
    const float* aff2_b = (const float*)d_in[8];
    const float* ffn1_w = (const float*)d_in[9];
    const float* ffn1_b = (const float*)d_in[10];
    const float* ffn2_w = (const float*)d_in[11];
    const float* ffn2_b = (const float*)d_in[12];
    const float* ln1_s  = (const float*)d_in[13];
    const float* ln1_b  = (const float*)d_in[14];
    const float* ln2_s  = (const float*)d_in[15];
    const float* ln2_b  = (const float*)d_in[16];
    const float* head_w = (const float*)d_in[17];
    const float* head_b = (const float*)d_in[18];

    // fp32 workspace carve (~61 MB)
    float* x      = (float*)d_ws;                 // [4096,512]
    float* qkv    = x      + (size_t)N_ * E_;     // [4096,1536]
    float* attb   = qkv    + (size_t)N_ * E3_;    // [4096,512]  attention out, then out1
    float* h1     = attb   + (size_t)N_ * E_;     // [4096,512]  relu hidden
    float* y2     = h1     + (size_t)N_ * E_;     // [4096,512]  aff2/ffn2 out
    float* logits = y2     + (size_t)N_ * E_;     // [4096,128]
    float* rowl   = logits + (size_t)N_ * V_;     // [4096]

    float* out_logits = (float*)d_out;
    float* out_loss   = out_logits + (size_t)N_ * V_;

    embed_kernel<<<dim3((N_ * E_) / 256), 256, 0, stream>>>(toks, emb, x);

    for (int l = 0; l < L_; ++l) {
        gemm_bias<<<dim3(E3_ / 64, N_ / 64), 256, 0, stream>>>(
            x, qkv_w + (size_t)l * E3_ * E_, qkv_b + (size_t)l * E3_, qkv, N_, E3_, E_, 0);
        attn_kernel<<<dim3(16, 32), 256, 0, stream>>>(qkv, attb);
        gemm_bias<<<dim3(E_ / 64, N_ / 64), 256, 0, stream>>>(
            attb, aff1_w + (size_t)l * E_ * E_, aff1_b + (size_t)l * E_, h1, N_, E_, E_, 1);
        gemm_bias<<<dim3(E_ / 64, N_ / 64), 256, 0, stream>>>(
            h1, aff2_w + (size_t)l * E_ * E_, aff2_b + (size_t)l * E_, y2, N_, E_, E_, 0);
        add_ln_kernel<<<dim3(N_), 256, 0, stream>>>(
            y2, x, ln1_s + (size_t)l * E_, ln1_b + (size_t)l * E_, attb);   // out1 -> attb
        gemm_bias<<<dim3(E_ / 64, N_ / 64), 256, 0, stream>>>(
            attb, ffn1_w + (size_t)l * E_ * E_, ffn1_b + (size_t)l * E_, h1, N_, E_, E_, 1);
        gemm_bias<<<dim3(E_ / 64, N_ / 64), 256, 0, stream>>>(
            h1, ffn2_w + (size_t)l * E_ * E_, ffn2_b + (size_t)l * E_, y2, N_, E_, E_, 0);
        add_ln_kernel<<<dim3(N_), 256, 0, stream>>>(
            attb, y2, ln2_s + (size_t)l * E_, ln2_b + (size_t)l * E_, x);   // new x
    }

    gemm_bias<<<dim3(V_ / 64, N_ / 64), 256, 0, stream>>>(
        x, head_w, head_b, logits, N_, V_, E_, 0);
    loss_row_kernel<<<dim3(N_), 128, 0, stream>>>(logits, tgts, out_logits, rowl);
    loss_reduce_kernel<<<dim3(1), 256, 0, stream>>>(rowl, out_loss);
}

// Round 3
// 1279.689 us; speedup vs baseline: 3.0790x; 3.0790x over previous
//
#include <hip/hip_runtime.h>

// 8-layer transformer LM forward. V=128, E=512, L=8, H=8, B=4, T=1024.
// Round 3: bf16 MFMA (16x16x32) for all GEMMs + flash attention.
// Residual/LN chain kept fp32; activations mirrored to bf16 for MFMA A-operands.

#define V_  128
#define E_  512
#define L_  8
#define H_  8
#define B_  4
#define T_  1024
#define N_  (B_*T_)    // 4096 tokens
#define DH_ 64
#define E3_ 1536

typedef unsigned short ushort_t;
typedef __attribute__((ext_vector_type(8))) short   bf16x8;   // MFMA A/B frag (4 VGPRs)
typedef __attribute__((ext_vector_type(4))) float   floatx4;  // MFMA C/D frag

__device__ __forceinline__ unsigned short f2bf(float f) {
    union { float f; unsigned int i; } v; v.f = f;
    unsigned int x = v.i;
    return (unsigned short)((x + 0x7fffu + ((x >> 16) & 1u)) >> 16);  // RNE
}
__device__ __forceinline__ float bf2f(unsigned short u) {
    union { unsigned int i; float f; } v; v.i = ((unsigned int)u) << 16; return v.f;
}
__device__ __forceinline__ void gload_lds16(const void* g, void* l) {
    __builtin_amdgcn_global_load_lds(
        (const __attribute__((address_space(1))) unsigned int*)g,
        (__attribute__((address_space(3))) unsigned int*)l, 16, 0, 0);
}

// ---------------- fp32 -> bf16 convert (weights) ----------------
__global__ void cvt_kernel(const float* __restrict__ src, unsigned short* __restrict__ dst, int n) {
    int i = (blockIdx.x * blockDim.x + threadIdx.x) * 4;
    if (i >= n) return;
    float4 v = *(const float4*)(src + i);
    ushort4 o; o.x = f2bf(v.x); o.y = f2bf(v.y); o.z = f2bf(v.z); o.w = f2bf(v.w);
    *(ushort4*)(dst + i) = o;
}

// ---------------- embedding: write fp32 + bf16 ----------------
__global__ void embed_kernel(const int* __restrict__ tok, const float* __restrict__ emb,
                             float* __restrict__ xf, unsigned short* __restrict__ xb) {
    int idx = blockIdx.x * blockDim.x + threadIdx.x;
    if (idx >= N_ * E_) return;
    int n = idx >> 9;
    int e = idx & (E_ - 1);
    float v = emb[tok[n] * E_ + e];
    xf[idx] = v; xb[idx] = f2bf(v);
}

// ---------------- MFMA GEMM: C[m,n] = act(A[m,:]·W[n,:] + bias[n]) ----------------
// A bf16 [M,K], W bf16 [N,K] (both K-contiguous). BM=128, BN=64, BK=64.
// 256 threads = 4 waves; wave w -> rows 32w..32w+31 (2 frag-rows) x 64 cols (4 frag-cols).
template<int RELU, int WF, int WB>
__global__ __launch_bounds__(256) void gemm_mfma(
    const unsigned short* __restrict__ A, const unsigned short* __restrict__ W,
    const float* __restrict__ bias, float* __restrict__ Cf, unsigned short* __restrict__ Cb,
    int M, int Nout, int K)
{
    __shared__ unsigned short Asm[128 * 64];
    __shared__ unsigned short Bsm[64 * 64];
    int tid = threadIdx.x;
    int wv = tid >> 6, ln = tid & 63;
    int lquad = ln >> 4, lmod = ln & 15;
    int m0 = blockIdx.y * 128, n0 = blockIdx.x * 64;

    floatx4 acc[2][4] = {};

    for (int k0 = 0; k0 < K; k0 += 64) {
        __syncthreads();
        // stage A tile 128x64 bf16 (16 KB): 4 width-16 loads/thread
        #pragma unroll
        for (int c = 0; c < 4; ++c) {
            int e = 8 * (tid + 256 * c);            // element index in tile
            int r = e >> 6, kk = e & 63;
            gload_lds16(A + (size_t)(m0 + r) * K + k0 + kk,
                        Asm + 512 * wv + 2048 * c); // wave-uniform base; lane adds *16B
        }
        // stage B tile 64x64 bf16 (8 KB): 2 loads/thread
        #pragma unroll
        for (int c = 0; c < 2; ++c) {
            int e = 8 * (tid + 256 * c);
            int r = e >> 6, kk = e & 63;
            gload_lds16(W + (size_t)(n0 + r) * K + k0 + kk,
                        Bsm + 512 * wv + 2048 * c);
        }
        __syncthreads();   // compiler drains vmcnt before s_barrier
        #pragma unroll
        for (int ks = 0; ks < 2; ++ks) {
            bf16x8 af[2], bfr[4];
            #pragma unroll
            for (int i = 0; i < 2; ++i)
                af[i] = *(const bf16x8*)&Asm[(32 * wv + 16 * i + lmod) * 64 + ks * 32 + lquad * 8];
            #pragma unroll
            for (int j = 0; j < 4; ++j)
                bfr[j] = *(const bf16x8*)&Bsm[(16 * j + lmod) * 64 + ks * 32 + lquad * 8];
            #pragma unroll
            for (int i = 0; i < 2; ++i)
                #pragma unroll
                for (int j = 0; j < 4; ++j)
                    acc[i][j] = __builtin_amdgcn_mfma_f32_16x16x32_bf16(af[i], bfr[j], acc[i][j], 0, 0, 0);
        }
    }
    // epilogue: C row = m0+32wv+16i+4*lquad+v, col = n0+16j+lmod
    #pragma unroll
    for (int i = 0; i < 2; ++i)
        #pragma unroll
        for (int j = 0; j < 4; ++j) {
            int n = n0 + 16 * j + lmod;
            float bj = bias[n];
            #pragma unroll
            for (int v = 0; v < 4; ++v) {
                int m = m0 + 32 * wv + 16 * i + 4 * lquad + v;
                float val = acc[i][j][v] + bj;
                if (RELU) val = fmaxf(val, 0.f);
                if (WF) Cf[(size_t)m * Nout + n] = val;
                if (WB) Cb[(size_t)m * Nout + n] = f2bf(val);
            }
        }
}

// ---------------- MFMA flash attention ----------------
// Grid (16 q-tiles, 32 b*h); 256 threads = 4 waves; wave w owns q-rows 16w..16w+15.
// Mask quirk: masked scores are ZERO (participate in softmax as exp(0)).
// Fully-masked k-tiles (kt > qt): skip QK^T, P = exp(-m) uniform.
__global__ __launch_bounds__(256) void attn_mfma(const unsigned short* __restrict__ qkv,
                                                 unsigned short* __restrict__ outb)
{
    __shared__ unsigned short Qs[64 * 64];  // [q][d]
    __shared__ unsigned short Ks[64 * 64];  // [k][d]
    __shared__ unsigned short Vt[64 * 64];  // [d][k]
    __shared__ unsigned short Ps[64 * 64];  // [q][k]

    int tid = threadIdx.x;
    int wv = tid >> 6, ln = tid & 63;
    int lquad = ln >> 4, lmod = ln & 15;
    int qt = blockIdx.x, bh = blockIdx.y;
    int b = bh >> 3, h = bh & 7;
    int q0 = qt * 64;
    const float scale = 0.125f;
    size_t base = (size_t)b * T_ * E3_ + (size_t)h * (3 * DH_);

    // load Q tile (64x64 bf16), natural layout
    for (int c = tid; c < 512; c += 256) {
        int r = c >> 3, cc = (c & 7) * 8;
        *(uint4*)&Qs[r * 64 + cc] = *(const uint4*)&qkv[base + (size_t)(q0 + r) * E3_ + cc];
    }

    float mrow[4], lrow[4];
    floatx4 Oa[4] = {};
    #pragma unroll
    for (int v = 0; v < 4; ++v) { mrow[v] = -1e30f; lrow[v] = 0.f; }

    for (int kt = 0; kt < 16; ++kt) {
        int k0 = kt * 64;
        bool fmask = (k0 > q0 + 63);   // block-uniform
        __syncthreads();               // prior readers of Ks/Vt/Ps done
        if (!fmask) {
            for (int c = tid; c < 512; c += 256) {
                int r = c >> 3, cc = (c & 7) * 8;
                *(uint4*)&Ks[r * 64 + cc] =
                    *(const uint4*)&qkv[base + (size_t)(k0 + r) * E3_ + DH_ + cc];
            }
        }
        for (int c = tid; c < 512; c += 256) {     // V transposed -> Vt[d][k]
            int r = c >> 3, cc = (c & 7) * 8;
            uint4 raw = *(const uint4*)&qkv[base + (size_t)(k0 + r) * E3_ + 2 * DH_ + cc];
            const unsigned short* pv = (const unsigned short*)&raw;
            #pragma unroll
            for (int i = 0; i < 8; ++i) Vt[(cc + i) * 64 + r] = pv[i];
        }
        __syncthreads();

        if (!fmask) {
            // S strip = Q[16 rows] · K^T  (4 col-frags, 2 k-steps over d)
            floatx4 sacc[4] = {};
            #pragma unroll
            for (int ks = 0; ks < 2; ++ks) {
                bf16x8 aq = *(const bf16x8*)&Qs[(16 * wv + lmod) * 64 + ks * 32 + lquad * 8];
                #pragma unroll
                for (int j = 0; j < 4; ++j) {
                    bf16x8 bk = *(const bf16x8*)&Ks[(16 * j + lmod) * 64 + ks * 32 + lquad * 8];
                    sacc[j] = __builtin_amdgcn_mfma_f32_16x16x32_bf16(aq, bk, sacc[j], 0, 0, 0);
                }
            }
            // online softmax update (rows 16wv+4lquad+v; cols k0+16j+lmod)
            float sv[4][4], p[4][4], tm[4];
            #pragma unroll
            for (int v = 0; v < 4; ++v) {
                int qg = q0 + 16 * wv + 4 * lquad + v;
                float mx = -1e30f;
                #pragma unroll
                for (int j = 0; j < 4; ++j) {
                    int kg = k0 + 16 * j + lmod;
                    float s = (kg <= qg) ? sacc[j][v] * scale : 0.f;
                    sv[j][v] = s; mx = fmaxf(mx, s);
                }
                tm[v] = mx;
            }
            #pragma unroll
            for (int v = 0; v < 4; ++v)
                #pragma unroll
                for (int msk = 1; msk < 16; msk <<= 1)
                    tm[v] = fmaxf(tm[v], __shfl_xor(tm[v], msk));
            #pragma unroll
            for (int v = 0; v < 4; ++v) {
                float mn = fmaxf(mrow[v], tm[v]);
                float al = __expf(mrow[v] - mn);
                mrow[v] = mn;
                float rs = 0.f;
                #pragma unroll
                for (int j = 0; j < 4; ++j) { p[j][v] = __expf(sv[j][v] - mn); rs += p[j][v]; }
                #pragma unroll
                for (int msk = 1; msk < 16; msk <<= 1) rs += __shfl_xor(rs, msk);
                lrow[v] = lrow[v] * al + rs;
                #pragma unroll
                for (int f = 0; f < 4; ++f) Oa[f][v] *= al;
                int qr = (16 * wv + 4 * lquad + v) * 64;
                #pragma unroll
                for (int j = 0; j < 4; ++j) Ps[qr + 16 * j + lmod] = f2bf(p[j][v]);
            }
        } else {
            // all scores 0: P = exp(-m_new) uniform, 64 keys
            #pragma unroll
            for (int v = 0; v < 4; ++v) {
                float mn = fmaxf(mrow[v], 0.f);
                float al = __expf(mrow[v] - mn);
                float p0 = __expf(-mn);
                mrow[v] = mn;
                lrow[v] = lrow[v] * al + 64.f * p0;
                #pragma unroll
                for (int f = 0; f < 4; ++f) Oa[f][v] *= al;
                unsigned short pb = f2bf(p0);
                int qr = (16 * wv + 4 * lquad + v) * 64;
                #pragma unroll
                for (int j = 0; j < 4; ++j) Ps[qr + 16 * j + lmod] = pb;
            }
        }
        __syncthreads();   // Ps ready
        // O strip += P[16 x 64] · V[64 x 64]
        #pragma unroll
        for (int ks = 0; ks < 2; ++ks) {
            bf16x8 ap = *(const bf16x8*)&Ps[(16 * wv + lmod) * 64 + ks * 32 + lquad * 8];
            #pragma unroll
            for (int f = 0; f < 4; ++f) {
                bf16x8 bv = *(const bf16x8*)&Vt[(16 * f + lmod) * 64 + ks * 32 + lquad * 8];
                Oa[f] = __builtin_amdgcn_mfma_f32_16x16x32_bf16(ap, bv, Oa[f], 0, 0, 0);
            }
        }
    }
    // normalize + store bf16 (transpose-back via index mapping)
    #pragma unroll
    for (int f = 0; f < 4; ++f)
        #pragma unroll
        for (int v = 0; v < 4; ++v) {
            int q = q0 + 16 * wv + 4 * lquad + v;
            float o = Oa[f][v] / lrow[v];
            outb[(size_t)(b * T_ + q) * E_ + h * DH_ + 16 * f + lmod] = f2bf(o);
        }
}

// ---------------- residual add + LayerNorm: fp32 in, fp32+bf16 out ----------------
__global__ __launch_bounds__(256) void add_ln_kernel(
    const float* __restrict__ a, const float* __restrict__ r,
    const float* __restrict__ s, const float* __restrict__ bpar,
    float* __restrict__ outF, unsigned short* __restrict__ outB)
{
    int n = blockIdx.x;
    int tid = threadIdx.x;
    int e = tid * 2;
    float2 va = *(const float2*)&a[(size_t)n * E_ + e];
    float2 vr = *(const float2*)&r[(size_t)n * E_ + e];
    float v0 = va.x + vr.x, v1 = va.y + vr.y;

    __shared__ float red[4];
    int lane = tid & 63, w = tid >> 6;

    float lsum = v0 + v1;
    #pragma unroll
    for (int off = 32; off; off >>= 1) lsum += __shfl_down(lsum, off, 64);
    if (lane == 0) red[w] = lsum;
    __syncthreads();
    float mu = (red[0] + red[1] + red[2] + red[3]) * (1.f / 512.f);
    __syncthreads();

    float d0 = v0 - mu, d1 = v1 - mu;
    float lss = d0 * d0 + d1 * d1;
    #pragma unroll
    for (int off = 32; off; off >>= 1) lss += __shfl_down(lss, off, 64);
    if (lane == 0) red[w] = lss;
    __syncthreads();
    float var = (red[0] + red[1] + red[2] + red[3]) * (1.f / 512.f);
    float rstd = rsqrtf(var + 1e-5f);

    float o0 = d0 * rstd * s[e]     + bpar[e];
    float o1 = d1 * rstd * s[e + 1] + bpar[e + 1];
    outF[(size_t)n * E_ + e]     = o0;
    outF[(size_t)n * E_ + e + 1] = o1;
    outB[(size_t)n * E_ + e]     = f2bf(o0);
    outB[(size_t)n * E_ + e + 1] = f2bf(o1);
}

// ---------------- per-row loss + fp32 logits out ----------------
__global__ __launch_bounds__(128) void loss_row_kernel(
    const float* __restrict__ logits, const int* __restrict__ tgt,
    float* __restrict__ out_logits, float* __restrict__ rowloss)
{
    int n = blockIdx.x, i = threadIdx.x;
    float x = logits[(size_t)n * V_ + i];
    out_logits[(size_t)n * V_ + i] = x;

    __shared__ float redA[2], redB[2];
    __shared__ float xt;
    int lane = i & 63, w = i >> 6;
    if (i == tgt[n]) xt = x;

    float m = x;
    #pragma unroll
    for (int off = 32; off; off >>= 1) m = fmaxf(m, __shfl_down(m, off, 64));
    if (lane == 0) redA[w] = m;
    __syncthreads();
    m = fmaxf(redA[0], redA[1]);
    __syncthreads();

    float ev = __expf(x - m);
    float se = ev, sx = x;
    #pragma unroll
    for (int off = 32; off; off >>= 1) {
        se += __shfl_down(se, off, 64);
        sx += __shfl_down(sx, off, 64);
    }
    if (lane == 0) { redA[w] = se; redB[w] = sx; }
    __syncthreads();
    if (i == 0) {
        float seT = redA[0] + redA[1], sxT = redB[0] + redB[1];
        float lse = m + __logf(seT);
        float nll = lse - xt;
        float smooth = lse - sxT * (1.f / 128.f);
        rowloss[n] = 0.9f * nll + 0.1f * smooth;
    }
}

__global__ __launch_bounds__(256) void loss_reduce_kernel(
    const float* __restrict__ rowloss, float* __restrict__ out)
{
    int tid = threadIdx.x;
    float sm = 0.f;
    for (int idx = tid; idx < N_; idx += 256) sm += rowloss[idx];
    #pragma unroll
    for (int off = 32; off; off >>= 1) sm += __shfl_down(sm, off, 64);
    __shared__ float red[4];
    int lane = tid & 63, w = tid >> 6;
    if (lane == 0) red[w] = sm;
    __syncthreads();
    if (tid == 0) out[0] = (red[0] + red[1] + red[2] + red[3]) * (1.f / (float)N_);
}

extern "C" void kernel_launch(void* const* d_in, const int* in_sizes, int n_in,
                              void* d_out, int out_size, void* d_ws, size_t ws_size,
                              hipStream_t stream)
{
    (void)in_sizes; (void)n_in; (void)out_size; (void)ws_size;
    const int* toks     = (const int*)d_in[0];
    const int* tgts     = (const int*)d_in[1];
    const float* emb    = (const float*)d_in[2];
    const float* qkv_w  = (const float*)d_in[3];
    const float* qkv_b  = (const float*)d_in[4];
    const float* aff1_w = (const float*)d_in[5];
    const float* aff1_b = (const float*)d_in[6];
    const float* aff2_w = (const float*)d_in[7];
    const float* aff2_b = (const float*)d_in[8];
    const float* ffn1_w = (const float*)d_in[9];
    const float* ffn1_b = (const float*)d_in[10];
    const float* ffn2_w = (const float*)d_in[11];
    const float* ffn2_b = (const float*)d_in[12];
    const float* ln1_s  = (const float*)d_in[13];
    const float* ln1_b  = (const float*)d_in[14];
    const float* ln2_s  = (const float*)d_in[15];
    const float* ln2_b  = (const float*)d_in[16];
    const float* head_w = (const float*)d_in[17];
    const float* head_b = (const float*)d_in[18];

    // ---- workspace carve (~84 MB) ----
    char* p = (char*)d_ws;
    auto carve = [&](size_t bytes) { char* r = p; p += (bytes + 255) & ~(size_t)255; return (void*)r; };
    unsigned short* wb_qkv  = (unsigned short*)carve((size_t)L_ * E3_ * E_ * 2);
    unsigned short* wb_aff1 = (unsigned short*)carve((size_t)L_ * E_ * E_ * 2);
    unsigned short* wb_aff2 = (unsigned short*)carve((size_t)L_ * E_ * E_ * 2);
    unsigned short* wb_ffn1 = (unsigned short*)carve((size_t)L_ * E_ * E_ * 2);
    unsigned short* wb_ffn2 = (unsigned short*)carve((size_t)L_ * E_ * E_ * 2);
    unsigned short* wb_head = (unsigned short*)carve((size_t)V_ * E_ * 2);
    float*          x_f     = (float*)carve((size_t)N_ * E_ * 4);
    unsigned short* x_b     = (unsigned short*)carve((size_t)N_ * E_ * 2);
    unsigned short* qkv_bf  = (unsigned short*)carve((size_t)N_ * E3_ * 2);
    unsigned short* att_b   = (unsigned short*)carve((size_t)N_ * E_ * 2);
    unsigned short* h_b     = (unsigned short*)carve((size_t)N_ * E_ * 2);
    float*          y_f     = (float*)carve((size_t)N_ * E_ * 4);
    float*          o1_f    = (float*)carve((size_t)N_ * E_ * 4);
    unsigned short* o1_b    = (unsigned short*)carve((size_t)N_ * E_ * 2);
    float*          logits  = (float*)carve((size_t)N_ * V_ * 4);
    float*          rowl    = (float*)carve((size_t)N_ * 4);

    float* out_logits = (float*)d_out;
    float* out_loss   = out_logits + (size_t)N_ * V_;

    // ---- weight conversion (per call; inputs restored each call) ----
    int n_qkv = L_ * E3_ * E_, n_sq = L_ * E_ * E_, n_hd = V_ * E_;
    cvt_kernel<<<dim3(n_qkv / 1024), 256, 0, stream>>>(qkv_w,  wb_qkv,  n_qkv);
    cvt_kernel<<<dim3(n_sq  / 1024), 256, 0, stream>>>(aff1_w, wb_aff1, n_sq);
    cvt_kernel<<<dim3(n_sq  / 1024), 256, 0, stream>>>(aff2_w, wb_aff2, n_sq);
    cvt_kernel<<<dim3(n_sq  / 1024), 256, 0, stream>>>(ffn1_w, wb_ffn1, n_sq);
    cvt_kernel<<<dim3(n_sq  / 1024), 256, 0, stream>>>(ffn2_w, wb_ffn2, n_sq);
    cvt_kernel<<<dim3(n_hd  / 1024), 256, 0, stream>>>(head_w, wb_head, n_hd);

    embed_kernel<<<dim3((N_ * E_) / 256), 256, 0, stream>>>(toks, emb, x_f, x_b);

    for (int l = 0; l < L_; ++l) {
        gemm_mfma<0,0,1><<<dim3(E3_/64, N_/128), 256, 0, stream>>>(
            x_b, wb_qkv + (size_t)l * E3_ * E_, qkv_b + (size_t)l * E3_,
            nullptr, qkv_bf, N_, E3_, E_);
        attn_mfma<<<dim3(16, 32), 256, 0, stream>>>(qkv_bf, att_b);
        gemm_mfma<1,0,1><<<dim3(E_/64, N_/128), 256, 0, stream>>>(
            att_b, wb_aff1 + (size_t)l * E_ * E_, aff1_b + (size_t)l * E_,
            nullptr, h_b, N_, E_, E_);
        gemm_mfma<0,1,0><<<dim3(E_/64, N_/128), 256, 0, stream>>>(
            h_b, wb_aff2 + (size_t)l * E_ * E_, aff2_b + (size_t)l * E_,
            y_f, nullptr, N_, E_, E_);
        add_ln_kernel<<<dim3(N_), 256, 0, stream>>>(
            y_f, x_f, ln1_s + (size_t)l * E_, ln1_b + (size_t)l * E_, o1_f, o1_b);
        gemm_mfma<1,0,1><<<dim3(E_/64, N_/128), 256, 0, stream>>>(
            o1_b, wb_ffn1 + (size_t)l * E_ * E_, ffn1_b + (size_t)l * E_,
            nullptr, h_b, N_, E_, E_);
        gemm_mfma<0,1,0><<<dim3(E_/64, N_/128), 256, 0, stream>>>(
            h_b, wb_ffn2 + (size_t)l * E_ * E_, ffn2_b + (size_t)l * E_,
            y_f, nullptr, N_, E_, E_);
        add_ln_kernel<<<dim3(N_), 256, 0, stream>>>(
            o1_f, y_f, ln2_s + (size_t)l * E_, ln2_b + (size_t)l * E_, x_f, x_b);
    }

    gemm_mfma<0,1,0><<<dim3(V_/64, N_/128), 256, 0, stream>>>(
        x_b, wb_head, head_b, logits, nullptr, N_, V_, E_);
    loss_row_kernel<<<dim3(N_), 128, 0, stream>>>(logits, tgts, out_logits, rowl);
    loss_reduce_kernel<<<dim3(1), 256, 0, stream>>>(rowl, out_loss);
}

// Round 4
// 1185.596 us; speedup vs baseline: 3.3234x; 1.0794x over previous
//
#include <hip/hip_runtime.h>

// 8-layer transformer LM forward. V=128, E=512, L=8, H=8, B=4, T=1024.
// Round 4: attention overhaul — XOR-swizzled LDS, coalesced V-transpose,
// masked-suffix trick (k-loop kt<=qt only), no max-tracking softmax (scores
// LN-bounded; masked score==0 => p==1 exactly), grid x=bh for L2 locality.

#define V_  128
#define E_  512
#define L_  8
#define H_  8
#define B_  4
#define T_  1024
#define N_  (B_*T_)    // 4096 tokens
#define DH_ 64
#define E3_ 1536

typedef unsigned short ushort_t;
typedef __attribute__((ext_vector_type(8))) short   bf16x8;   // MFMA A/B frag
typedef __attribute__((ext_vector_type(4))) float   floatx4;  // MFMA C/D frag

// swizzled LDS offset (ushort units): row-major 64-wide, 8-elem blocks XORed by row&7
#define SW(row,k8) (((row) << 6) + ((((k8) ^ ((row) & 7))) << 3))

__device__ __forceinline__ unsigned short f2bf(float f) {
    union { float f; unsigned int i; } v; v.f = f;
    unsigned int x = v.i;
    return (unsigned short)((x + 0x7fffu + ((x >> 16) & 1u)) >> 16);  // RNE
}
__device__ __forceinline__ float bf2f(unsigned short u) {
    union { unsigned int i; float f; } v; v.i = ((unsigned int)u) << 16; return v.f;
}
__device__ __forceinline__ void gload_lds16(const void* g, void* l) {
    __builtin_amdgcn_global_load_lds(
        (const __attribute__((address_space(1))) unsigned int*)g,
        (__attribute__((address_space(3))) unsigned int*)l, 16, 0, 0);
}

// ---------------- fp32 -> bf16 convert (weights) ----------------
__global__ void cvt_kernel(const float* __restrict__ src, unsigned short* __restrict__ dst, int n) {
    int i = (blockIdx.x * blockDim.x + threadIdx.x) * 4;
    if (i >= n) return;
    float4 v = *(const float4*)(src + i);
    ushort4 o; o.x = f2bf(v.x); o.y = f2bf(v.y); o.z = f2bf(v.z); o.w = f2bf(v.w);
    *(ushort4*)(dst + i) = o;
}

// ---------------- embedding: write fp32 + bf16 ----------------
__global__ void embed_kernel(const int* __restrict__ tok, const float* __restrict__ emb,
                             float* __restrict__ xf, unsigned short* __restrict__ xb) {
    int idx = blockIdx.x * blockDim.x + threadIdx.x;
    if (idx >= N_ * E_) return;
    int n = idx >> 9;
    int e = idx & (E_ - 1);
    float v = emb[tok[n] * E_ + e];
    xf[idx] = v; xb[idx] = f2bf(v);
}

// ---------------- MFMA GEMM (unchanged from round 3) ----------------
template<int RELU, int WF, int WB>
__global__ __launch_bounds__(256) void gemm_mfma(
    const unsigned short* __restrict__ A, const unsigned short* __restrict__ W,
    const float* __restrict__ bias, float* __restrict__ Cf, unsigned short* __restrict__ Cb,
    int M, int Nout, int K)
{
    __shared__ unsigned short Asm[128 * 64];
    __shared__ unsigned short Bsm[64 * 64];
    int tid = threadIdx.x;
    int wv = tid >> 6, ln = tid & 63;
    int lquad = ln >> 4, lmod = ln & 15;
    int m0 = blockIdx.y * 128, n0 = blockIdx.x * 64;

    floatx4 acc[2][4] = {};

    for (int k0 = 0; k0 < K; k0 += 64) {
        __syncthreads();
        #pragma unroll
        for (int c = 0; c < 4; ++c) {
            int e = 8 * (tid + 256 * c);
            int r = e >> 6, kk = e & 63;
            gload_lds16(A + (size_t)(m0 + r) * K + k0 + kk, Asm + 512 * wv + 2048 * c);
        }
        #pragma unroll
        for (int c = 0; c < 2; ++c) {
            int e = 8 * (tid + 256 * c);
            int r = e >> 6, kk = e & 63;
            gload_lds16(W + (size_t)(n0 + r) * K + k0 + kk, Bsm + 512 * wv + 2048 * c);
        }
        __syncthreads();
        #pragma unroll
        for (int ks = 0; ks < 2; ++ks) {
            bf16x8 af[2], bfr[4];
            #pragma unroll
            for (int i = 0; i < 2; ++i)
                af[i] = *(const bf16x8*)&Asm[(32 * wv + 16 * i + lmod) * 64 + ks * 32 + lquad * 8];
            #pragma unroll
            for (int j = 0; j < 4; ++j)
                bfr[j] = *(const bf16x8*)&Bsm[(16 * j + lmod) * 64 + ks * 32 + lquad * 8];
            #pragma unroll
            for (int i = 0; i < 2; ++i)
                #pragma unroll
                for (int j = 0; j < 4; ++j)
                    acc[i][j] = __builtin_amdgcn_mfma_f32_16x16x32_bf16(af[i], bfr[j], acc[i][j], 0, 0, 0);
        }
    }
    #pragma unroll
    for (int i = 0; i < 2; ++i)
        #pragma unroll
        for (int j = 0; j < 4; ++j) {
            int n = n0 + 16 * j + lmod;
            float bj = bias[n];
            #pragma unroll
            for (int v = 0; v < 4; ++v) {
                int m = m0 + 32 * wv + 16 * i + 4 * lquad + v;
                float val = acc[i][j][v] + bj;
                if (RELU) val = fmaxf(val, 0.f);
                if (WF) Cf[(size_t)m * Nout + n] = val;
                if (WB) Cb[(size_t)m * Nout + n] = f2bf(val);
            }
        }
}

// ---------------- V suffix sums: vsuf[bh][kt][d] = sum_{k>=64kt} V[k][d] ----------------
__global__ __launch_bounds__(256) void vsuffix_kernel(const unsigned short* __restrict__ qkv,
                                                      float* __restrict__ vsuf) {
    int bh = blockIdx.x; int b = bh >> 3, h = bh & 7;
    int tid = threadIdx.x; int d = tid & 63, g = tid >> 6;
    __shared__ float part[4][64];
    __shared__ float run[64];
    if (tid < 64) run[tid] = 0.f;
    size_t base = (size_t)b * T_ * E3_ + h * 192 + 128;
    for (int kt = 15; kt >= 1; --kt) {        // only kt>=1 ever read (qt+1)
        float s = 0.f;
        #pragma unroll
        for (int i = 0; i < 16; ++i) {
            int t = kt * 64 + g * 16 + i;
            s += bf2f(qkv[base + (size_t)t * E3_ + d]);
        }
        part[g][d] = s;
        __syncthreads();
        if (tid < 64) {
            float r = run[tid] + part[0][tid] + part[1][tid] + part[2][tid] + part[3][tid];
            run[tid] = r;
            vsuf[((size_t)bh * 16 + kt) * 64 + tid] = r;
        }
        __syncthreads();
    }
}

// ---------------- MFMA flash attention (swizzled, suffix-tricked) ----------------
// Grid (32 bh, 16 qt); 256 threads = 4 waves. Masked scores are ZERO (=> p=1).
__global__ __launch_bounds__(256) void attn_mfma(const unsigned short* __restrict__ qkv,
                                                 const float* __restrict__ vsuf,
                                                 unsigned short* __restrict__ outb)
{
    __shared__ unsigned short Qs[64 * 64];  // [q][d] swizzled
    __shared__ unsigned short Ks[64 * 64];  // [k][d] swizzled
    __shared__ unsigned short Vt[64 * 64];  // [d][k] swizzled
    __shared__ unsigned short Ps[64 * 64];  // [q][k] swizzled

    int tid = threadIdx.x;
    int wv = tid >> 6, ln = tid & 63;
    int lquad = ln >> 4, lmod = ln & 15;
    int bh = blockIdx.x, qt = blockIdx.y;
    int b = bh >> 3, h = bh & 7;
    int q0 = qt * 64;
    const float scale = 0.125f;
    size_t base = (size_t)b * T_ * E3_ + h * 192;

    // Q tile, swizzled
    for (int c = tid; c < 512; c += 256) {
        int r = c >> 3, k8 = c & 7;
        *(uint4*)&Qs[SW(r, k8)] = *(const uint4*)&qkv[base + (size_t)(q0 + r) * E3_ + k8 * 8];
    }

    float lrow[4] = {0.f, 0.f, 0.f, 0.f};
    floatx4 Oa[4] = {};

    for (int kt = 0; kt <= qt; ++kt) {
        int k0 = kt * 64;
        __syncthreads();   // Qs ready (1st iter); Ks/Vt/Ps readers done (later iters)
        // K tile, swizzled (coalesced uint4)
        for (int c = tid; c < 512; c += 256) {
            int r = c >> 3, k8 = c & 7;
            *(uint4*)&Ks[SW(r, k8)] = *(const uint4*)&qkv[base + (size_t)(k0 + r) * E3_ + 64 + k8 * 8];
        }
        // V transposed: lane=d (coalesced 128B strided u16 loads), swizzled b128 writes
        {
            int d = ln, kseg = wv;     // kseg wave-uniform
            unsigned short vals[16];
            #pragma unroll
            for (int i = 0; i < 16; ++i)
                vals[i] = qkv[base + (size_t)(k0 + kseg * 16 + i) * E3_ + 128 + d];
            #pragma unroll
            for (int hf = 0; hf < 2; ++hf) {
                union { unsigned short u[8]; uint4 v; } pk;
                #pragma unroll
                for (int i = 0; i < 8; ++i) pk.u[i] = vals[hf * 8 + i];
                *(uint4*)&Vt[SW(d, kseg * 2 + hf)] = pk.v;
            }
        }
        __syncthreads();

        // S strip = Q[16 rows]·K^T
        floatx4 sacc[4] = {};
        #pragma unroll
        for (int ks = 0; ks < 2; ++ks) {
            bf16x8 aq = *(const bf16x8*)&Qs[SW(16 * wv + lmod, ks * 4 + lquad)];
            #pragma unroll
            for (int j = 0; j < 4; ++j) {
                bf16x8 bk = *(const bf16x8*)&Ks[SW(16 * j + lmod, ks * 4 + lquad)];
                sacc[j] = __builtin_amdgcn_mfma_f32_16x16x32_bf16(aq, bk, sacc[j], 0, 0, 0);
            }
        }
        // softmax terms, no max-subtraction (scores LN-bounded; masked => exp(0)=1)
        #pragma unroll
        for (int v = 0; v < 4; ++v) {
            int qg = q0 + 16 * wv + 4 * lquad + v;
            int row = 16 * wv + 4 * lquad + v;
            float rs = 0.f;
            #pragma unroll
            for (int j = 0; j < 4; ++j) {
                int kg = k0 + 16 * j + lmod;
                float p = (kg <= qg) ? __expf(sacc[j][v] * scale) : 1.0f;
                rs += p;
                int col = 16 * j + lmod;
                Ps[SW(row, col >> 3) + (col & 7)] = f2bf(p);
            }
            #pragma unroll
            for (int msk = 1; msk < 16; msk <<= 1) rs += __shfl_xor(rs, msk);
            lrow[v] += rs;
        }
        __syncthreads();   // Ps ready
        // O strip += P·V
        #pragma unroll
        for (int ks = 0; ks < 2; ++ks) {
            bf16x8 ap = *(const bf16x8*)&Ps[SW(16 * wv + lmod, ks * 4 + lquad)];
            #pragma unroll
            for (int f = 0; f < 4; ++f) {
                bf16x8 bv = *(const bf16x8*)&Vt[SW(16 * f + lmod, ks * 4 + lquad)];
                Oa[f] = __builtin_amdgcn_mfma_f32_16x16x32_bf16(ap, bv, Oa[f], 0, 0, 0);
            }
        }
    }

    // fully-masked suffix tiles: score==0 => p=1; O += sum_suffix V; l += count
    if (qt < 15) {
        float Km = (float)((15 - qt) * 64);
        const float* vs = vsuf + ((size_t)bh * 16 + qt + 1) * 64;
        #pragma unroll
        for (int v = 0; v < 4; ++v) lrow[v] += Km;
        #pragma unroll
        for (int f = 0; f < 4; ++f) {
            float sv = vs[16 * f + lmod];
            #pragma unroll
            for (int v = 0; v < 4; ++v) Oa[f][v] += sv;
        }
    }

    #pragma unroll
    for (int f = 0; f < 4; ++f)
        #pragma unroll
        for (int v = 0; v < 4; ++v) {
            int q = q0 + 16 * wv + 4 * lquad + v;
            outb[(size_t)(b * T_ + q) * E_ + h * DH_ + 16 * f + lmod] = f2bf(Oa[f][v] / lrow[v]);
        }
}

// ---------------- residual add + LayerNorm ----------------
__global__ __launch_bounds__(256) void add_ln_kernel(
    const float* __restrict__ a, const float* __restrict__ r,
    const float* __restrict__ s, const float* __restrict__ bpar,
    float* __restrict__ outF, unsigned short* __restrict__ outB)
{
    int n = blockIdx.x;
    int tid = threadIdx.x;
    int e = tid * 2;
    float2 va = *(const float2*)&a[(size_t)n * E_ + e];
    float2 vr = *(const float2*)&r[(size_t)n * E_ + e];
    float v0 = va.x + vr.x, v1 = va.y + vr.y;

    __shared__ float red[4];
    int lane = tid & 63, w = tid >> 6;

    float lsum = v0 + v1;
    #pragma unroll
    for (int off = 32; off; off >>= 1) lsum += __shfl_down(lsum, off, 64);
    if (lane == 0) red[w] = lsum;
    __syncthreads();
    float mu = (red[0] + red[1] + red[2] + red[3]) * (1.f / 512.f);
    __syncthreads();

    float d0 = v0 - mu, d1 = v1 - mu;
    float lss = d0 * d0 + d1 * d1;
    #pragma unroll
    for (int off = 32; off; off >>= 1) lss += __shfl_down(lss, off, 64);
    if (lane == 0) red[w] = lss;
    __syncthreads();
    float var = (red[0] + red[1] + red[2] + red[3]) * (1.f / 512.f);
    float rstd = rsqrtf(var + 1e-5f);

    float o0 = d0 * rstd * s[e]     + bpar[e];
    float o1 = d1 * rstd * s[e + 1] + bpar[e + 1];
    outF[(size_t)n * E_ + e]     = o0;
    outF[(size_t)n * E_ + e + 1] = o1;
    outB[(size_t)n * E_ + e]     = f2bf(o0);
    outB[(size_t)n * E_ + e + 1] = f2bf(o1);
}

// ---------------- per-row loss + fp32 logits out ----------------
__global__ __launch_bounds__(128) void loss_row_kernel(
    const float* __restrict__ logits, const int* __restrict__ tgt,
    float* __restrict__ out_logits, float* __restrict__ rowloss)
{
    int n = blockIdx.x, i = threadIdx.x;
    float x = logits[(size_t)n * V_ + i];
    out_logits[(size_t)n * V_ + i] = x;

    __shared__ float redA[2], redB[2];
    __shared__ float xt;
    int lane = i & 63, w = i >> 6;
    if (i == tgt[n]) xt = x;

    float m = x;
    #pragma unroll
    for (int off = 32; off; off >>= 1) m = fmaxf(m, __shfl_down(m, off, 64));
    if (lane == 0) redA[w] = m;
    __syncthreads();
    m = fmaxf(redA[0], redA[1]);
    __syncthreads();

    float ev = __expf(x - m);
    float se = ev, sx = x;
    #pragma unroll
    for (int off = 32; off; off >>= 1) {
        se += __shfl_down(se, off, 64);
        sx += __shfl_down(sx, off, 64);
    }
    if (lane == 0) { redA[w] = se; redB[w] = sx; }
    __syncthreads();
    if (i == 0) {
        float seT = redA[0] + redA[1], sxT = redB[0] + redB[1];
        float lse = m + __logf(seT);
        float nll = lse - xt;
        float smooth = lse - sxT * (1.f / 128.f);
        rowloss[n] = 0.9f * nll + 0.1f * smooth;
    }
}

__global__ __launch_bounds__(256) void loss_reduce_kernel(
    const float* __restrict__ rowloss, float* __restrict__ out)
{
    int tid = threadIdx.x;
    float sm = 0.f;
    for (int idx = tid; idx < N_; idx += 256) sm += rowloss[idx];
    #pragma unroll
    for (int off = 32; off; off >>= 1) sm += __shfl_down(sm, off, 64);
    __shared__ float red[4];
    int lane = tid & 63, w = tid >> 6;
    if (lane == 0) red[w] = sm;
    __syncthreads();
    if (tid == 0) out[0] = (red[0] + red[1] + red[2] + red[3]) * (1.f / (float)N_);
}

extern "C" void kernel_launch(void* const* d_in, const int* in_sizes, int n_in,
                              void* d_out, int out_size, void* d_ws, size_t ws_size,
                              hipStream_t stream)
{
    (void)in_sizes; (void)n_in; (void)out_size; (void)ws_size;
    const int* toks     = (const int*)d_in[0];
    const int* tgts     = (const int*)d_in[1];
    const float* emb    = (const float*)d_in[2];
    const float* qkv_w  = (const float*)d_in[3];
    const float* qkv_b  = (const float*)d_in[4];
    const float* aff1_w = (const float*)d_in[5];
    const float* aff1_b = (const float*)d_in[6];
    const float* aff2_w = (const float*)d_in[7];
    const float* aff2_b = (const float*)d_in[8];
    const float* ffn1_w = (const float*)d_in[9];
    const float* ffn1_b = (const float*)d_in[10];
    const float* ffn2_w = (const float*)d_in[11];
    const float* ffn2_b = (const float*)d_in[12];
    const float* ln1_s  = (const float*)d_in[13];
    const float* ln1_b  = (const float*)d_in[14];
    const float* ln2_s  = (const float*)d_in[15];
    const float* ln2_b  = (const float*)d_in[16];
    const float* head_w = (const float*)d_in[17];
    const float* head_b = (const float*)d_in[18];

    char* p = (char*)d_ws;
    auto carve = [&](size_t bytes) { char* r = p; p += (bytes + 255) & ~(size_t)255; return (void*)r; };
    unsigned short* wb_qkv  = (unsigned short*)carve((size_t)L_ * E3_ * E_ * 2);
    unsigned short* wb_aff1 = (unsigned short*)carve((size_t)L_ * E_ * E_ * 2);
    unsigned short* wb_aff2 = (unsigned short*)carve((size_t)L_ * E_ * E_ * 2);
    unsigned short* wb_ffn1 = (unsigned short*)carve((size_t)L_ * E_ * E_ * 2);
    unsigned short* wb_ffn2 = (unsigned short*)carve((size_t)L_ * E_ * E_ * 2);
    unsigned short* wb_head = (unsigned short*)carve((size_t)V_ * E_ * 2);
    float*          x_f     = (float*)carve((size_t)N_ * E_ * 4);
    unsigned short* x_b     = (unsigned short*)carve((size_t)N_ * E_ * 2);
    unsigned short* qkv_bf  = (unsigned short*)carve((size_t)N_ * E3_ * 2);
    unsigned short* att_b   = (unsigned short*)carve((size_t)N_ * E_ * 2);
    unsigned short* h_b     = (unsigned short*)carve((size_t)N_ * E_ * 2);
    float*          y_f     = (float*)carve((size_t)N_ * E_ * 4);
    float*          o1_f    = (float*)carve((size_t)N_ * E_ * 4);
    unsigned short* o1_b    = (unsigned short*)carve((size_t)N_ * E_ * 2);
    float*          logits  = (float*)carve((size_t)N_ * V_ * 4);
    float*          rowl    = (float*)carve((size_t)N_ * 4);
    float*          vsuf    = (float*)carve((size_t)32 * 16 * 64 * 4);

    float* out_logits = (float*)d_out;
    float* out_loss   = out_logits + (size_t)N_ * V_;

    int n_qkv = L_ * E3_ * E_, n_sq = L_ * E_ * E_, n_hd = V_ * E_;
    cvt_kernel<<<dim3(n_qkv / 1024), 256, 0, stream>>>(qkv_w,  wb_qkv,  n_qkv);
    cvt_kernel<<<dim3(n_sq  / 1024), 256, 0, stream>>>(aff1_w, wb_aff1, n_sq);
    cvt_kernel<<<dim3(n_sq  / 1024), 256, 0, stream>>>(aff2_w, wb_aff2, n_sq);
    cvt_kernel<<<dim3(n_sq  / 1024), 256, 0, stream>>>(ffn1_w, wb_ffn1, n_sq);
    cvt_kernel<<<dim3(n_sq  / 1024), 256, 0, stream>>>(ffn2_w, wb_ffn2, n_sq);
    cvt_kernel<<<dim3(n_hd  / 1024), 256, 0, stream>>>(head_w, wb_head, n_hd);

    embed_kernel<<<dim3((N_ * E_) / 256), 256, 0, stream>>>(toks, emb, x_f, x_b);

    for (int l = 0; l < L_; ++l) {
        gemm_mfma<0,0,1><<<dim3(E3_/64, N_/128), 256, 0, stream>>>(
            x_b, wb_qkv + (size_t)l * E3_ * E_, qkv_b + (size_t)l * E3_,
            nullptr, qkv_bf, N_, E3_, E_);
        vsuffix_kernel<<<dim3(32), 256, 0, stream>>>(qkv_bf, vsuf);
        attn_mfma<<<dim3(32, 16), 256, 0, stream>>>(qkv_bf, vsuf, att_b);
        gemm_mfma<1,0,1><<<dim3(E_/64, N_/128), 256, 0, stream>>>(
            att_b, wb_aff1 + (size_t)l * E_ * E_, aff1_b + (size_t)l * E_,
            nullptr, h_b, N_, E_, E_);
        gemm_mfma<0,1,0><<<dim3(E_/64, N_/128), 256, 0, stream>>>(
            h_b, wb_aff2 + (size_t)l * E_ * E_, aff2_b + (size_t)l * E_,
            y_f, nullptr, N_, E_, E_);
        add_ln_kernel<<<dim3(N_), 256, 0, stream>>>(
            y_f, x_f, ln1_s + (size_t)l * E_, ln1_b + (size_t)l * E_, o1_f, o1_b);
        gemm_mfma<1,0,1><<<dim3(E_/64, N_/128), 256, 0, stream>>>(
            o1_b, wb_ffn1 + (size_t)l * E_ * E_, ffn1_b + (size_t)l * E_,
            nullptr, h_b, N_, E_, E_);
        gemm_mfma<0,1,0><<<dim3(E_/64, N_/128), 256, 0, stream>>>(
            h_b, wb_ffn2 + (size_t)l * E_ * E_, ffn2_b + (size_t)l * E_,
            y_f, nullptr, N_, E_, E_);
        add_ln_kernel<<<dim3(N_), 256, 0, stream>>>(
            o1_f, y_f, ln2_s + (size_t)l * E_, ln2_b + (size_t)l * E_, x_f, x_b);
    }

    gemm_mfma<0,1,0><<<dim3(V_/64, N_/128), 256, 0, stream>>>(
        x_b, wb_head, head_b, logits, nullptr, N_, V_, E_);
    loss_row_kernel<<<dim3(N_), 128, 0, stream>>>(logits, tgts, out_logits, rowl);
    loss_reduce_kernel<<<dim3(1), 256, 0, stream>>>(rowl, out_loss);
}